// Round 10
// baseline (539.517 us; speedup 1.0000x reference)
//
#include <hip/hip_runtime.h>

#define BB 8
#define LL 512
#define HH 8
#define BIGV (1e9f)

typedef unsigned short u16;
typedef __attribute__((ext_vector_type(8))) short bf16x8;
typedef __attribute__((ext_vector_type(4))) short s16x4;
typedef __attribute__((ext_vector_type(4))) float f32x4;

#define MFMA(a,b,c) __builtin_amdgcn_mfma_f32_16x16x32_bf16(a,b,c,0,0,0)

__device__ __forceinline__ u16 f2b(float f){
  unsigned u = __float_as_uint(f);
  u = (u + 0x7fffu + ((u>>16)&1u)) >> 16;
  return (u16)u;
}
__device__ __forceinline__ float b2f(u16 s){ return __uint_as_float(((unsigned)s)<<16); }
__device__ __forceinline__ bf16x8 ldb8(const u16* p){ return *(const bf16x8*)p; }

__device__ __forceinline__ float wred_max(float v){
  #pragma unroll
  for(int off=32;off>0;off>>=1) v = fmaxf(v, __shfl_xor(v, off, 64));
  return v;
}
__device__ __forceinline__ float wred_sum(float v){
  #pragma unroll
  for(int off=32;off>0;off>>=1) v += __shfl_xor(v, off, 64);
  return v;
}
__device__ __forceinline__ float g16_sum(float v){
  v += __shfl_xor(v,1,64); v += __shfl_xor(v,2,64);
  v += __shfl_xor(v,4,64); v += __shfl_xor(v,8,64);
  return v;
}

// ---- tables: T4t[c][b][a], Tt2[c][a][b], Gt[a][j], Gt2[j][a] ----
__global__ void kp_prep(const float* __restrict__ T, const float* __restrict__ gw,
                        u16* __restrict__ T4t, u16* __restrict__ Tt2,
                        u16* __restrict__ Gt, u16* __restrict__ Gt2){
  int idx = blockIdx.x*256 + threadIdx.x;   // < 32768
  { int c=idx>>12, b=(idx>>6)&63, a=idx&63; T4t[idx] = f2b(T[(a*64+b)*8+c]); }
  { int c=idx>>12, a=(idx>>6)&63, b=idx&63; Tt2[idx] = f2b(T[(a*64+b)*8+c]); }
  if(idx < 4096){
    int a=idx>>6, j=idx&63;
    Gt[idx]  = f2b(gw[j*64+a]);   // Gt[a][j]
    Gt2[idx] = f2b(gw[idx]);      // Gt2[j][a]
  }
}

// ---- k0: unary = (x+pe)*m1 ; qzstate = unary ; mf = mask as float ----
__global__ void k0_init(const float* __restrict__ x, const int* __restrict__ mask,
                        float* __restrict__ unary, float* __restrict__ qzstate,
                        float* __restrict__ mf){
  int idx = blockIdx.x*256 + threadIdx.x;
  int d = idx & 63; int row = idx >> 6;
  int pos = row & (LL-1);
  int k2 = d & ~1;
  float div = __expf(-(float)k2 * 0.14391156962f);  // ln(10000)/64
  float arg = (float)pos * div;
  float pe = (d & 1) ? cosf(arg) : sinf(arg);
  float mk = (mask[row] != 0) ? 1.f : 0.f;
  float u = (x[idx] + pe) * mk;
  unary[idx] = u; qzstate[idx] = u;
  if(d == 0) mf[row] = mk;
}

// ---- kA: softmax64 -> qzb ; P2 softmax + Mg = P2@gw -> MgF ----
__global__ __launch_bounds__(256) void kA(const float* __restrict__ qzstate,
      const int* __restrict__ mask, const u16* __restrict__ Gt2, const u16* __restrict__ Gt,
      u16* __restrict__ qzb, float* __restrict__ MgF){
  __shared__ u16 qlds[64*72];
  __shared__ u16 P2s[64*72];
  int bid = blockIdx.x; int z = bid & 7, itile = bid >> 3;   // z-affine for XCD L2
  int t = threadIdx.x, lane = t&63, w = t>>6, l15 = lane&15, lhi = lane>>4;
  int rbase = z*LL + itile*64;
  for(int p=0;p<16;p++){
    int rl = w*16 + p, rg = rbase + rl;
    float v = qzstate[(size_t)rg*64 + lane];
    float mx = wred_max(v);
    float e = __expf(v - mx);
    float s = wred_sum(e);
    float mk = (mask[rg] != 0) ? 1.f : 0.f;
    u16 q = f2b(e/s*mk);
    qzb[(size_t)rg*64 + lane] = q;
    qlds[rl*72 + lane] = q;
  }
  __syncthreads();
  f32x4 f[4];
  {
    const u16* Ar = &qlds[(w*16 + l15)*72 + lhi*8];
    bf16x8 a0 = ldb8(Ar), a1 = ldb8(Ar+32);
    #pragma unroll
    for(int ct=0;ct<4;ct++){
      const u16* Br = Gt2 + (size_t)(ct*16 + l15)*64 + lhi*8;
      f32x4 acc = {0.f,0.f,0.f,0.f};
      acc = MFMA(a0, ldb8(Br), acc);
      acc = MFMA(a1, ldb8(Br+32), acc);
      f[ct] = acc;
    }
  }
  #pragma unroll
  for(int jj=0;jj<4;jj++){
    float ps = 0.f;
    #pragma unroll
    for(int ct=0;ct<4;ct++){ float e = __expf(f[ct][jj]); f[ct][jj] = e; ps += e; }
    float s = g16_sum(ps);
    float iv = 1.f/s;
    #pragma unroll
    for(int ct=0;ct<4;ct++)
      P2s[(w*16 + lhi*4 + jj)*72 + ct*16 + l15] = f2b(f[ct][jj]*iv);
  }
  __syncthreads();
  {
    const u16* Ar = &P2s[(w*16 + l15)*72 + lhi*8];
    bf16x8 a0 = ldb8(Ar), a1 = ldb8(Ar+32);
    #pragma unroll
    for(int nt=0;nt<4;nt++){
      const u16* Br = Gt + (size_t)(nt*16 + l15)*64 + lhi*8;
      f32x4 acc = {0.f,0.f,0.f,0.f};
      acc = MFMA(a0, ldb8(Br), acc);
      acc = MFMA(a1, ldb8(Br+32), acc);
      #pragma unroll
      for(int jj=0;jj<4;jj++)
        MgF[((size_t)rbase + w*16 + lhi*4 + jj)*64 + nt*16 + l15] = acc[jj];
    }
  }
}

// ---- k2: per (z,c): t1[i][b], t1t[b][i], t2t[a][j]  (all K=64 GEMMs) ----
__global__ __launch_bounds__(256) void k2(const u16* __restrict__ qzb,
      const u16* __restrict__ T4t, const u16* __restrict__ Tt2,
      u16* __restrict__ t1b, u16* __restrict__ t1t, u16* __restrict__ t2t){
  int bid = blockIdx.x; int z = bid&7, c = (bid>>3)&7, itile = bid>>6;
  int zc = z*8 + c;
  int t = threadIdx.x, lane = t&63, w = t>>6, l15 = lane&15, lhi = lane>>4;
  int i0 = itile*64;
  const u16* qA = qzb + ((size_t)z*LL + i0 + w*16 + l15)*64 + lhi*8;
  bf16x8 qa0 = ldb8(qA), qa1 = ldb8(qA+32);
  const u16* tA = T4t + c*4096 + (w*16 + l15)*64 + lhi*8;
  bf16x8 ta0 = ldb8(tA), ta1 = ldb8(tA+32);
  const u16* uA = Tt2 + c*4096 + (w*16 + l15)*64 + lhi*8;
  bf16x8 ua0 = ldb8(uA), ua1 = ldb8(uA+32);
  #pragma unroll
  for(int nt=0;nt<4;nt++){
    {
      const u16* Br = T4t + c*4096 + (nt*16 + l15)*64 + lhi*8;
      f32x4 acc = {0.f,0.f,0.f,0.f};
      acc = MFMA(qa0, ldb8(Br), acc);
      acc = MFMA(qa1, ldb8(Br+32), acc);
      #pragma unroll
      for(int jj=0;jj<4;jj++)
        t1b[((size_t)zc*LL + i0 + w*16 + lhi*4 + jj)*64 + nt*16 + l15] = f2b(acc[jj]);
    }
    const u16* Br = qzb + ((size_t)z*LL + i0 + nt*16 + l15)*64 + lhi*8;
    bf16x8 qb0 = ldb8(Br), qb1 = ldb8(Br+32);
    {
      f32x4 acc = {0.f,0.f,0.f,0.f};
      acc = MFMA(ta0, qb0, acc);
      acc = MFMA(ta1, qb1, acc);
      #pragma unroll
      for(int jj=0;jj<4;jj++)
        t1t[((size_t)zc*64 + w*16 + lhi*4 + jj)*LL + i0 + nt*16 + l15] = f2b(acc[jj]);
    }
    {
      f32x4 acc = {0.f,0.f,0.f,0.f};
      acc = MFMA(ua0, qb0, acc);
      acc = MFMA(ua1, qb1, acc);
      #pragma unroll
      for(int jj=0;jj<4;jj++)
        t2t[((size_t)zc*64 + w*16 + lhi*4 + jj)*LL + i0 + nt*16 + l15] = f2b(acc[jj]);
    }
  }
}

// ---- kF: 8 waves, 512 blocks, 2 panels; LDS 79.7KB -> 2 blocks/CU ----
// mi B-operand streams from L2-resident t2t inside the MFMA loop (round-8
// lesson: persistent reg tiles spill; round-5/7 lesson: z-affine t2t L2-hits).
__global__ __launch_bounds__(512, 4) void kF(const u16* __restrict__ t1b, const u16* __restrict__ qzb,
        const u16* __restrict__ t1t, const u16* __restrict__ t2t, const float* __restrict__ mf,
        u16* __restrict__ miP, u16* __restrict__ mjP){
  extern __shared__ char smem[];
  u16*   Pp   = (u16*)smem;                    // [32][520]  33280 B (unnormalized exp)
  u16*   PpT  = (u16*)(smem + 33280);          // [8w][64][40] 40960 B (normalized, wave-local)
  float* red  = (float*)(smem + 74240);        // [32][8]     1024 B
  float* redS = (float*)(smem + 75264);        // [32]         128 B
  u16*   stg32= (u16*)(smem + 75392);          // [32][68]    4352 B  (end 79744)
  u16*   stg  = (u16*)smem;                    // [512][72] dump (reuses Pp+PpT, 73728 B)
  int bid = blockIdx.x;
  int z = bid&7, c = (bid>>3)&7, it = bid>>6;   // it < 8
  int zc = z*8 + c;
  int t = threadIdx.x, lane = t&63, w = t>>6, l15 = lane&15, lhi = lane>>4;
  int jc0 = w*64;                               // wave's 64-wide j-slice
  int wr = w>>2, wc = w&3;                      // mi tile role (full K)
  float mfj[4];
  #pragma unroll
  for(int ct=0;ct<4;ct++) mfj[ct] = mf[z*LL + jc0 + ct*16 + l15];
  f32x4 mj[4][4];
  #pragma unroll
  for(int jt=0;jt<4;jt++)
    #pragma unroll
    for(int bt=0;bt<4;bt++) mj[jt][bt] = (f32x4){0.f,0.f,0.f,0.f};
  u16* PpTw = PpT + w*64*40;                    // wave-local transpose buffer

  for(int ip=0; ip<2; ++ip){
    int i0g = it*64 + ip*32;
    // ---- S panel (32 rows x wave's 64 cols) ----
    f32x4 S[2][4];
    #pragma unroll
    for(int rt=0;rt<2;rt++)
      #pragma unroll
      for(int ct=0;ct<4;ct++) S[rt][ct] = (f32x4){0.f,0.f,0.f,0.f};
    #pragma unroll
    for(int rt=0;rt<2;rt++){
      const u16* Ar = t1b + ((size_t)zc*LL + i0g + rt*16 + l15)*64 + lhi*8;
      bf16x8 a0 = ldb8(Ar), a1 = ldb8(Ar+32);
      #pragma unroll
      for(int ct=0;ct<4;ct++){
        const u16* Br = qzb + ((size_t)z*LL + jc0 + ct*16 + l15)*64 + lhi*8;
        S[rt][ct] = MFMA(a0, ldb8(Br), S[rt][ct]);
        S[rt][ct] = MFMA(a1, ldb8(Br+32), S[rt][ct]);
      }
    }
    // ---- mask/diag/exp (fixed max), partial row-sums, unnormalized Pp ----
    #pragma unroll
    for(int rt=0;rt<2;rt++)
      #pragma unroll
      for(int jj=0;jj<4;jj++){
        int rloc = rt*16 + lhi*4 + jj;
        int irow = i0g + rloc;
        float mfi = mf[z*LL + irow];
        float ps = 0.f;
        #pragma unroll
        for(int ct=0;ct<4;ct++){
          int jcol = jc0 + ct*16 + l15;
          float v = S[rt][ct][jj] - ((irow==jcol)?BIGV:0.f);
          float e = mfi * mfj[ct] * __expf(v);
          S[rt][ct][jj] = e; ps += e;
          Pp[rloc*520 + jcol] = f2b(e);        // unnormalized
        }
        ps = g16_sum(ps);
        if(l15 == 0) red[rloc*8 + w] = ps;
      }
    __syncthreads();                            // B1: Pp/red ready
    // ---- cooperative row-sum: red[32][8] -> redS[32] ----
    if(t < 256){
      float v = red[t];
      v += __shfl_xor(v,1,64); v += __shfl_xor(v,2,64); v += __shfl_xor(v,4,64);
      if((t&7)==0) redS[t>>3] = v;
    }
    __syncthreads();                            // B1.5: redS ready
    float ivv[2][4];
    #pragma unroll
    for(int rt=0;rt<2;rt++)
      #pragma unroll
      for(int jj=0;jj<4;jj++){
        float s = redS[rt*16 + lhi*4 + jj];
        ivv[rt][jj] = s > 0.f ? 1.f/s : 0.f;
      }
    // ---- normalized wave-local PpT (own 64-j slice; no barrier before mj) ----
    #pragma unroll
    for(int rt=0;rt<2;rt++)
      #pragma unroll
      for(int ct=0;ct<4;ct++){
        s16x4 v4 = { (short)f2b(S[rt][ct][0]*ivv[rt][0]), (short)f2b(S[rt][ct][1]*ivv[rt][1]),
                     (short)f2b(S[rt][ct][2]*ivv[rt][2]), (short)f2b(S[rt][ct][3]*ivv[rt][3]) };
        *(s16x4*)&PpTw[(ct*16 + l15)*40 + rt*16 + lhi*4] = v4;
      }
    // ---- mi: full K=512; A = Pp (unnorm, LDS), B = t2t (global, L2-hot) ----
    {
      f32x4 mia = {0.f,0.f,0.f,0.f};
      const u16* Ab = Pp + (wr*16 + l15)*520 + lhi*8;
      const u16* Bb = t2t + ((size_t)zc*64 + wc*16 + l15)*LL + lhi*8;
      #pragma unroll
      for(int ks=0;ks<16;ks++)
        mia = MFMA(ldb8(Ab + ks*32), ldb8(Bb + ks*32), mia);
      #pragma unroll
      for(int jj=0;jj<4;jj++)
        stg32[(wr*16 + lhi*4 + jj)*68 + wc*16 + l15] = f2b(mia[jj]*ivv[wr][jj]);
    }
    // ---- mj accumulate: A = own PpT (K=32), B = t1t (global, L2-hot) ----
    {
      bf16x8 av[4];
      #pragma unroll
      for(int jt=0;jt<4;jt++)
        av[jt] = ldb8(PpTw + (jt*16 + l15)*40 + lhi*8);
      #pragma unroll
      for(int bt=0;bt<4;bt++){
        bf16x8 b = ldb8(t1t + ((size_t)zc*64 + bt*16 + l15)*LL + i0g + lhi*8);
        #pragma unroll
        for(int jt=0;jt<4;jt++) mj[jt][bt] = MFMA(av[jt], b, mj[jt][bt]);
      }
    }
    __syncthreads();                            // B2: stg32 ready; Pp/PpT reads done
    // ---- mi store: 8B coalesced (overlaps next panel's front) ----
    {
      int r = t>>4, cc = t&15;
      *(s16x4*)&miP[((size_t)z*LL + i0g + r)*512 + c*64 + cc*4]
        = *(const s16x4*)&stg32[r*68 + cc*4];
    }
    // no trailing barrier: next panel writes Pp/red (read-complete pre-B2);
    // next stg32 write happens after next B1.5.
  }
  // ---- mj dump: single pass, stg[512][72] reuses dead Pp+PpT space ----
  #pragma unroll
  for(int jt=0;jt<4;jt++)
    #pragma unroll
    for(int bt=0;bt<4;bt++)
      #pragma unroll
      for(int jj=0;jj<4;jj++)
        stg[(jc0 + jt*16 + lhi*4 + jj)*72 + bt*16 + l15] = f2b(mj[jt][bt][jj]);
  __syncthreads();
  #pragma unroll
  for(int q=0;q<8;q++){
    int e = q*512 + t;
    int j = e >> 3, ch = e & 7;
    *(bf16x8*)&mjP[(((size_t)(it*8 + z))*LL + j)*512 + c*64 + ch*8]
      = *(const bf16x8*)&stg[j*72 + ch*8];
  }
}

// ---- k5c: out = (unary + Mg + sum_c miP + sum_{it,c} mjP) * m1 ----
__global__ __launch_bounds__(256) void k5c(const u16* __restrict__ miP, const u16* __restrict__ mjP,
      const float* __restrict__ MgF, const float* __restrict__ unary, const float* __restrict__ mf,
      float* __restrict__ outq){
  int bid = blockIdx.x; int z = bid&7, itile = bid>>3;   // itile < 16
  int t = threadIdx.x;
  int r = t>>3, c8 = t&7;
  int row = itile*32 + r;
  size_t gr = (size_t)z*LL + row;
  const float* mgp = &MgF[gr*64 + c8*8];
  f32x4 aclo = *(const f32x4*)mgp;
  f32x4 achi = *(const f32x4*)(mgp + 4);
  #pragma unroll
  for(int c=0;c<8;c++){
    bf16x8 v = ldb8(&miP[gr*512 + c*64 + c8*8]);
    aclo[0]+=b2f((u16)v[0]); aclo[1]+=b2f((u16)v[1]); aclo[2]+=b2f((u16)v[2]); aclo[3]+=b2f((u16)v[3]);
    achi[0]+=b2f((u16)v[4]); achi[1]+=b2f((u16)v[5]); achi[2]+=b2f((u16)v[6]); achi[3]+=b2f((u16)v[7]);
  }
  #pragma unroll
  for(int s=0;s<8;s++)
    #pragma unroll
    for(int c=0;c<8;c++){
      bf16x8 v = ldb8(&mjP[(((size_t)(s*8 + z))*LL + row)*512 + c*64 + c8*8]);
      aclo[0]+=b2f((u16)v[0]); aclo[1]+=b2f((u16)v[1]); aclo[2]+=b2f((u16)v[2]); aclo[3]+=b2f((u16)v[3]);
      achi[0]+=b2f((u16)v[4]); achi[1]+=b2f((u16)v[5]); achi[2]+=b2f((u16)v[6]); achi[3]+=b2f((u16)v[7]);
    }
  f32x4 u0 = *(const f32x4*)&unary[gr*64 + c8*8];
  f32x4 u1 = *(const f32x4*)&unary[gr*64 + c8*8 + 4];
  float mk = mf[gr];
  f32x4 o0, o1;
  #pragma unroll
  for(int k=0;k<4;k++){ o0[k] = (u0[k] + aclo[k]) * mk; o1[k] = (u1[k] + achi[k]) * mk; }
  *(f32x4*)&outq[gr*64 + c8*8]     = o0;
  *(f32x4*)&outq[gr*64 + c8*8 + 4] = o1;
}

extern "C" void kernel_launch(void* const* d_in, const int* in_sizes, int n_in,
                              void* d_out, int out_size, void* d_ws, size_t ws_size,
                              hipStream_t stream) {
  const float* x       = (const float*)d_in[0];
  const int*   mask    = (const int*)d_in[1];
  const float* ternary = (const float*)d_in[2];
  const float* gw      = (const float*)d_in[3];
  float* out = (float*)d_out;

  const size_t NE = (size_t)BB*LL*64;          // 262144
  char* p = (char*)d_ws;
  auto alloc = [&](size_t bytes)->void*{
    void* r = (void*)p; p += (bytes + 255) & ~(size_t)255; return r;
  };
  float* unary   = (float*)alloc(NE*4);
  float* qzstate = (float*)alloc(NE*4);
  float* mf      = (float*)alloc((size_t)BB*LL*4);
  u16*   qzb     = (u16*)alloc(NE*2);
  u16*   t1b     = (u16*)alloc((size_t)BB*HH*LL*64*2);   // 4.2 MB
  u16*   t1t     = (u16*)alloc((size_t)BB*HH*LL*64*2);   // 4.2 MB
  u16*   t2t     = (u16*)alloc((size_t)BB*HH*LL*64*2);   // 4.2 MB
  float* MgF     = (float*)alloc(NE*4);                  // 1 MB
  u16*   miP     = (u16*)alloc((size_t)BB*LL*512*2);     // 4.2 MB
  u16*   mjP     = (u16*)alloc((size_t)64*LL*512*2);     // 33.5 MB (8 it-partials)
  u16*   T4t     = (u16*)alloc(32768*2);
  u16*   Tt2     = (u16*)alloc(32768*2);
  u16*   Gt      = (u16*)alloc(4096*2);
  u16*   Gt2     = (u16*)alloc(4096*2);

  const int KF_LDS = 79744;  // Pp 33280 + PpT 40960 + red 1024 + redS 128 + stg32 4352
  hipFuncSetAttribute(reinterpret_cast<const void*>(kF),
                      hipFuncAttributeMaxDynamicSharedMemorySize, KF_LDS);

  kp_prep<<<128, 256, 0, stream>>>(ternary, gw, T4t, Tt2, Gt, Gt2);
  k0_init<<<(int)(NE/256), 256, 0, stream>>>(x, mask, unary, qzstate, mf);
  for(int it=0; it<4; ++it){
    kA<<<BB*8, 256, 0, stream>>>(qzstate, mask, Gt2, Gt, qzb, MgF);
    k2<<<512, 256, 0, stream>>>(qzb, T4t, Tt2, t1b, t1t, t2t);
    kF<<<512, 512, KF_LDS, stream>>>(t1b, qzb, t1t, t2t, mf, miP, mjP);
    float* outq = (it==3) ? out : qzstate;
    k5c<<<128, 256, 0, stream>>>(miP, mjP, MgF, unary, mf, outq);
  }
}

// Round 11
// 423.006 us; speedup vs baseline: 1.2754x; 1.2754x over previous
//
#include <hip/hip_runtime.h>

#define BB 8
#define LL 512
#define HH 8
#define BIGV (1e9f)

typedef unsigned short u16;
typedef __attribute__((ext_vector_type(8))) short bf16x8;
typedef __attribute__((ext_vector_type(4))) short s16x4;
typedef __attribute__((ext_vector_type(4))) float f32x4;

#define MFMA(a,b,c) __builtin_amdgcn_mfma_f32_16x16x32_bf16(a,b,c,0,0,0)

__device__ __forceinline__ u16 f2b(float f){
  unsigned u = __float_as_uint(f);
  u = (u + 0x7fffu + ((u>>16)&1u)) >> 16;
  return (u16)u;
}
__device__ __forceinline__ float b2f(u16 s){ return __uint_as_float(((unsigned)s)<<16); }
__device__ __forceinline__ bf16x8 ldb8(const u16* p){ return *(const bf16x8*)p; }

__device__ __forceinline__ float wred_max(float v){
  #pragma unroll
  for(int off=32;off>0;off>>=1) v = fmaxf(v, __shfl_xor(v, off, 64));
  return v;
}
__device__ __forceinline__ float wred_sum(float v){
  #pragma unroll
  for(int off=32;off>0;off>>=1) v += __shfl_xor(v, off, 64);
  return v;
}
__device__ __forceinline__ float g16_sum(float v){
  v += __shfl_xor(v,1,64); v += __shfl_xor(v,2,64);
  v += __shfl_xor(v,4,64); v += __shfl_xor(v,8,64);
  return v;
}

// ---- tables: T4t[c][b][a], Tt2[c][a][b], Gt[a][j], Gt2[j][a] ----
__global__ void kp_prep(const float* __restrict__ T, const float* __restrict__ gw,
                        u16* __restrict__ T4t, u16* __restrict__ Tt2,
                        u16* __restrict__ Gt, u16* __restrict__ Gt2){
  int idx = blockIdx.x*256 + threadIdx.x;   // < 32768
  { int c=idx>>12, b=(idx>>6)&63, a=idx&63; T4t[idx] = f2b(T[(a*64+b)*8+c]); }
  { int c=idx>>12, a=(idx>>6)&63, b=idx&63; Tt2[idx] = f2b(T[(a*64+b)*8+c]); }
  if(idx < 4096){
    int a=idx>>6, j=idx&63;
    Gt[idx]  = f2b(gw[j*64+a]);   // Gt[a][j]
    Gt2[idx] = f2b(gw[idx]);      // Gt2[j][a]
  }
}

// ---- k0: unary = (x+pe)*m1 ; qzstate = unary ; mf = mask as float ----
__global__ void k0_init(const float* __restrict__ x, const int* __restrict__ mask,
                        float* __restrict__ unary, float* __restrict__ qzstate,
                        float* __restrict__ mf){
  int idx = blockIdx.x*256 + threadIdx.x;
  int d = idx & 63; int row = idx >> 6;
  int pos = row & (LL-1);
  int k2 = d & ~1;
  float div = __expf(-(float)k2 * 0.14391156962f);  // ln(10000)/64
  float arg = (float)pos * div;
  float pe = (d & 1) ? cosf(arg) : sinf(arg);
  float mk = (mask[row] != 0) ? 1.f : 0.f;
  float u = (x[idx] + pe) * mk;
  unary[idx] = u; qzstate[idx] = u;
  if(d == 0) mf[row] = mk;
}

// ---- kA: softmax64 -> qzb ; P2 softmax + Mg = P2@gw -> MgF ----
__global__ __launch_bounds__(256) void kA(const float* __restrict__ qzstate,
      const int* __restrict__ mask, const u16* __restrict__ Gt2, const u16* __restrict__ Gt,
      u16* __restrict__ qzb, float* __restrict__ MgF){
  __shared__ u16 qlds[64*72];
  __shared__ u16 P2s[64*72];
  int bid = blockIdx.x; int z = bid & 7, itile = bid >> 3;   // z-affine for XCD L2
  int t = threadIdx.x, lane = t&63, w = t>>6, l15 = lane&15, lhi = lane>>4;
  int rbase = z*LL + itile*64;
  for(int p=0;p<16;p++){
    int rl = w*16 + p, rg = rbase + rl;
    float v = qzstate[(size_t)rg*64 + lane];
    float mx = wred_max(v);
    float e = __expf(v - mx);
    float s = wred_sum(e);
    float mk = (mask[rg] != 0) ? 1.f : 0.f;
    u16 q = f2b(e/s*mk);
    qzb[(size_t)rg*64 + lane] = q;
    qlds[rl*72 + lane] = q;
  }
  __syncthreads();
  f32x4 f[4];
  {
    const u16* Ar = &qlds[(w*16 + l15)*72 + lhi*8];
    bf16x8 a0 = ldb8(Ar), a1 = ldb8(Ar+32);
    #pragma unroll
    for(int ct=0;ct<4;ct++){
      const u16* Br = Gt2 + (size_t)(ct*16 + l15)*64 + lhi*8;
      f32x4 acc = {0.f,0.f,0.f,0.f};
      acc = MFMA(a0, ldb8(Br), acc);
      acc = MFMA(a1, ldb8(Br+32), acc);
      f[ct] = acc;
    }
  }
  #pragma unroll
  for(int jj=0;jj<4;jj++){
    float ps = 0.f;
    #pragma unroll
    for(int ct=0;ct<4;ct++){ float e = __expf(f[ct][jj]); f[ct][jj] = e; ps += e; }
    float s = g16_sum(ps);
    float iv = 1.f/s;
    #pragma unroll
    for(int ct=0;ct<4;ct++)
      P2s[(w*16 + lhi*4 + jj)*72 + ct*16 + l15] = f2b(f[ct][jj]*iv);
  }
  __syncthreads();
  {
    const u16* Ar = &P2s[(w*16 + l15)*72 + lhi*8];
    bf16x8 a0 = ldb8(Ar), a1 = ldb8(Ar+32);
    #pragma unroll
    for(int nt=0;nt<4;nt++){
      const u16* Br = Gt + (size_t)(nt*16 + l15)*64 + lhi*8;
      f32x4 acc = {0.f,0.f,0.f,0.f};
      acc = MFMA(a0, ldb8(Br), acc);
      acc = MFMA(a1, ldb8(Br+32), acc);
      #pragma unroll
      for(int jj=0;jj<4;jj++)
        MgF[((size_t)rbase + w*16 + lhi*4 + jj)*64 + nt*16 + l15] = acc[jj];
    }
  }
}

// ---- k2: per (z,c): t1[i][b], t1t[b][i], t2t[a][j]  (all K=64 GEMMs) ----
__global__ __launch_bounds__(256) void k2(const u16* __restrict__ qzb,
      const u16* __restrict__ T4t, const u16* __restrict__ Tt2,
      u16* __restrict__ t1b, u16* __restrict__ t1t, u16* __restrict__ t2t){
  int bid = blockIdx.x; int z = bid&7, c = (bid>>3)&7, itile = bid>>6;
  int zc = z*8 + c;
  int t = threadIdx.x, lane = t&63, w = t>>6, l15 = lane&15, lhi = lane>>4;
  int i0 = itile*64;
  const u16* qA = qzb + ((size_t)z*LL + i0 + w*16 + l15)*64 + lhi*8;
  bf16x8 qa0 = ldb8(qA), qa1 = ldb8(qA+32);
  const u16* tA = T4t + c*4096 + (w*16 + l15)*64 + lhi*8;
  bf16x8 ta0 = ldb8(tA), ta1 = ldb8(tA+32);
  const u16* uA = Tt2 + c*4096 + (w*16 + l15)*64 + lhi*8;
  bf16x8 ua0 = ldb8(uA), ua1 = ldb8(uA+32);
  #pragma unroll
  for(int nt=0;nt<4;nt++){
    {
      const u16* Br = T4t + c*4096 + (nt*16 + l15)*64 + lhi*8;
      f32x4 acc = {0.f,0.f,0.f,0.f};
      acc = MFMA(qa0, ldb8(Br), acc);
      acc = MFMA(qa1, ldb8(Br+32), acc);
      #pragma unroll
      for(int jj=0;jj<4;jj++)
        t1b[((size_t)zc*LL + i0 + w*16 + lhi*4 + jj)*64 + nt*16 + l15] = f2b(acc[jj]);
    }
    const u16* Br = qzb + ((size_t)z*LL + i0 + nt*16 + l15)*64 + lhi*8;
    bf16x8 qb0 = ldb8(Br), qb1 = ldb8(Br+32);
    {
      f32x4 acc = {0.f,0.f,0.f,0.f};
      acc = MFMA(ta0, qb0, acc);
      acc = MFMA(ta1, qb1, acc);
      #pragma unroll
      for(int jj=0;jj<4;jj++)
        t1t[((size_t)zc*64 + w*16 + lhi*4 + jj)*LL + i0 + nt*16 + l15] = f2b(acc[jj]);
    }
    {
      f32x4 acc = {0.f,0.f,0.f,0.f};
      acc = MFMA(ua0, qb0, acc);
      acc = MFMA(ua1, qb1, acc);
      #pragma unroll
      for(int jj=0;jj<4;jj++)
        t2t[((size_t)zc*64 + w*16 + lhi*4 + jj)*LL + i0 + nt*16 + l15] = f2b(acc[jj]);
    }
  }
}

// ---- kF: 512 thr, grid (z,c,it<4,h<2); block = 4 panels x 32 rows, K/b-half h ----
// 74.6KB LDS -> 2 blocks/CU; per-wave persistent regs ~64 (no spill at 128 cap).
__global__ __launch_bounds__(512, 4) void kF(const u16* __restrict__ t1b, const u16* __restrict__ qzb,
        const u16* __restrict__ t1t, const u16* __restrict__ t2t, const float* __restrict__ mf,
        u16* __restrict__ miP2, u16* __restrict__ mjP){
  extern __shared__ char smem[];
  u16*   t2sh = (u16*)smem;                    // [64][264] 33792 B (h-half of t2t[zc])
  u16*   Pph  = (u16*)(smem + 33792);          // [32][264] 16896 B (unnorm exp, h-half cols)
  u16*   PpTs = (u16*)(smem + 50688);          // [8w][2][16][36] 18432 B (ping-pong)
  float* red  = (float*)(smem + 69120);        // [32][8]   1024 B
  float* redS = (float*)(smem + 70144);        // [32]       128 B
  u16*   stg32= (u16*)(smem + 70272);          // [32][68]  4352 B  (end 74624)
  u16*   stg  = (u16*)smem;                    // [512][40] dump 40960 B (reuses t2sh+Pph)
  int bid = blockIdx.x;
  int z = bid&7, c = (bid>>3)&7, it = (bid>>6)&3, h = bid>>8;
  int zc = z*8 + c;
  int t = threadIdx.x, lane = t&63, w = t>>6, l15 = lane&15, lhi = lane>>4;
  int jc0 = w*64;                               // wave's 64-wide j-slice
  int wl = w & 3;                               // position within h-half group
  int wh = ((w>>2) == h);                       // this wave's j-slice is in h-half
  int wr = w>>2, wc = w&3;                      // mi tile role (K-half h)
  // ---- stage t2t[zc][:, h*256..+256] -> t2sh ----
  #pragma unroll
  for(int m=0;m<4;m++){
    int e = (m*512 + t)*8;
    int a = e >> 8, j = e & 255;
    *(bf16x8*)&t2sh[a*264 + j] = ldb8(t2t + ((size_t)zc*64 + a)*LL + h*256 + j);
  }
  float mfj[4];
  #pragma unroll
  for(int ct=0;ct<4;ct++) mfj[ct] = mf[z*LL + jc0 + ct*16 + l15];
  f32x4 mj[4][2];
  #pragma unroll
  for(int jt=0;jt<4;jt++){ mj[jt][0] = (f32x4){0,0,0,0}; mj[jt][1] = (f32x4){0,0,0,0}; }
  u16* Pw = PpTs + w*2*16*36;

  for(int ip=0; ip<4; ++ip){
    int i0g = it*128 + ip*32;
    // ---- S panel (32 rows x wave's 64 cols) ----
    f32x4 S[2][4];
    #pragma unroll
    for(int rt=0;rt<2;rt++)
      #pragma unroll
      for(int ct=0;ct<4;ct++) S[rt][ct] = (f32x4){0.f,0.f,0.f,0.f};
    #pragma unroll
    for(int rt=0;rt<2;rt++){
      const u16* Ar = t1b + ((size_t)zc*LL + i0g + rt*16 + l15)*64 + lhi*8;
      bf16x8 a0 = ldb8(Ar), a1 = ldb8(Ar+32);
      #pragma unroll
      for(int ct=0;ct<4;ct++){
        const u16* Br = qzb + ((size_t)z*LL + jc0 + ct*16 + l15)*64 + lhi*8;
        S[rt][ct] = MFMA(a0, ldb8(Br), S[rt][ct]);
        S[rt][ct] = MFMA(a1, ldb8(Br+32), S[rt][ct]);
      }
    }
    // ---- mask/diag/exp (fixed max), partial row-sums, h-half unnormalized Pph ----
    #pragma unroll
    for(int rt=0;rt<2;rt++)
      #pragma unroll
      for(int jj=0;jj<4;jj++){
        int rloc = rt*16 + lhi*4 + jj;
        int irow = i0g + rloc;
        float mfi = mf[z*LL + irow];
        float ps = 0.f;
        #pragma unroll
        for(int ct=0;ct<4;ct++){
          int jcol = jc0 + ct*16 + l15;
          float v = S[rt][ct][jj] - ((irow==jcol)?BIGV:0.f);
          float e = mfi * mfj[ct] * __expf(v);
          S[rt][ct][jj] = e; ps += e;
          if(wh) Pph[rloc*264 + wl*64 + ct*16 + l15] = f2b(e);
        }
        ps = g16_sum(ps);
        if(l15 == 0) red[rloc*8 + w] = ps;
      }
    __syncthreads();                            // B1: Pph/red (and t2sh, ip=0) ready
    if(t < 256){
      float v = red[t];
      v += __shfl_xor(v,1,64); v += __shfl_xor(v,2,64); v += __shfl_xor(v,4,64);
      if((t&7)==0) redS[t>>3] = v;
    }
    __syncthreads();                            // B1.5: redS ready
    float ivv[2][4];
    #pragma unroll
    for(int rt=0;rt<2;rt++)
      #pragma unroll
      for(int jj=0;jj<4;jj++){
        float s = redS[rt*16 + lhi*4 + jj];
        ivv[rt][jj] = s > 0.f ? 1.f/s : 0.f;
      }
    // ---- mj: per jt, wave-local ping-pong transpose tile then 2 MFMA (b-half h) ----
    {
      bf16x8 bmj0 = ldb8(t1t + ((size_t)zc*64 + (h*2+0)*16 + l15)*LL + i0g + lhi*8);
      bf16x8 bmj1 = ldb8(t1t + ((size_t)zc*64 + (h*2+1)*16 + l15)*LL + i0g + lhi*8);
      #pragma unroll
      for(int jt=0;jt<4;jt++){
        u16* Ps = Pw + (jt&1)*16*36;
        #pragma unroll
        for(int rt=0;rt<2;rt++){
          s16x4 v4 = { (short)f2b(S[rt][jt][0]*ivv[rt][0]), (short)f2b(S[rt][jt][1]*ivv[rt][1]),
                       (short)f2b(S[rt][jt][2]*ivv[rt][2]), (short)f2b(S[rt][jt][3]*ivv[rt][3]) };
          *(s16x4*)&Ps[l15*36 + rt*16 + lhi*4] = v4;
        }
        bf16x8 av = ldb8(Ps + l15*36 + lhi*8);
        mj[jt][0] = MFMA(av, bmj0, mj[jt][0]);
        mj[jt][1] = MFMA(av, bmj1, mj[jt][1]);
      }
    }
    // ---- mi: K-half h; A = Pph (unnorm, LDS), B = t2sh (LDS); iv post-scale ----
    {
      f32x4 mia = {0.f,0.f,0.f,0.f};
      const u16* Ab = Pph + (wr*16 + l15)*264 + lhi*8;
      const u16* Bb = t2sh + (wc*16 + l15)*264 + lhi*8;
      #pragma unroll
      for(int ks=0;ks<8;ks++)
        mia = MFMA(ldb8(Ab + ks*32), ldb8(Bb + ks*32), mia);
      #pragma unroll
      for(int jj=0;jj<4;jj++)
        stg32[(wr*16 + lhi*4 + jj)*68 + wc*16 + l15] = f2b(mia[jj]*ivv[wr][jj]);
    }
    __syncthreads();                            // B2: stg32 ready; Pph/red reads done
    // ---- mi half store: 8B coalesced to miP2[h] ----
    {
      int r = t>>4, cc = t&15;
      *(s16x4*)&miP2[(((size_t)(h*8 + z))*LL + i0g + r)*512 + c*64 + cc*4]
        = *(const s16x4*)&stg32[r*68 + cc*4];
    }
    // no trailing barrier: next panel's Pph/red writes are fenced by next B1;
    // next stg32 write happens after next B1.5.
  }
  // ---- mj dump: single pass; stg[512][40] reuses dead t2sh/Pph ----
  #pragma unroll
  for(int jt=0;jt<4;jt++)
    #pragma unroll
    for(int bt=0;bt<2;bt++)
      #pragma unroll
      for(int jj=0;jj<4;jj++)
        stg[(jc0 + jt*16 + lhi*4 + jj)*40 + bt*16 + l15] = f2b(mj[jt][bt][jj]);
  __syncthreads();
  #pragma unroll
  for(int q=0;q<4;q++){
    int e = q*512 + t;
    int j = e >> 2, ch = e & 3;
    *(bf16x8*)&mjP[(((size_t)(it*8 + z))*LL + j)*512 + c*64 + h*32 + ch*8]
      = *(const bf16x8*)&stg[j*40 + ch*8];
  }
}

// ---- k5c: out = (unary + Mg + sum_{h,c} miP2 + sum_{it,c} mjP) * m1 ----
__global__ __launch_bounds__(256) void k5c(const u16* __restrict__ miP2, const u16* __restrict__ mjP,
      const float* __restrict__ MgF, const float* __restrict__ unary, const float* __restrict__ mf,
      float* __restrict__ outq){
  int bid = blockIdx.x; int z = bid&7, itile = bid>>3;   // itile < 16
  int t = threadIdx.x;
  int r = t>>3, c8 = t&7;
  int row = itile*32 + r;
  size_t gr = (size_t)z*LL + row;
  const float* mgp = &MgF[gr*64 + c8*8];
  f32x4 aclo = *(const f32x4*)mgp;
  f32x4 achi = *(const f32x4*)(mgp + 4);
  #pragma unroll
  for(int h=0;h<2;h++)
    #pragma unroll
    for(int c=0;c<8;c++){
      bf16x8 v = ldb8(&miP2[(((size_t)(h*8 + z))*LL + row)*512 + c*64 + c8*8]);
      aclo[0]+=b2f((u16)v[0]); aclo[1]+=b2f((u16)v[1]); aclo[2]+=b2f((u16)v[2]); aclo[3]+=b2f((u16)v[3]);
      achi[0]+=b2f((u16)v[4]); achi[1]+=b2f((u16)v[5]); achi[2]+=b2f((u16)v[6]); achi[3]+=b2f((u16)v[7]);
    }
  #pragma unroll
  for(int s=0;s<4;s++)
    #pragma unroll
    for(int c=0;c<8;c++){
      bf16x8 v = ldb8(&mjP[(((size_t)(s*8 + z))*LL + row)*512 + c*64 + c8*8]);
      aclo[0]+=b2f((u16)v[0]); aclo[1]+=b2f((u16)v[1]); aclo[2]+=b2f((u16)v[2]); aclo[3]+=b2f((u16)v[3]);
      achi[0]+=b2f((u16)v[4]); achi[1]+=b2f((u16)v[5]); achi[2]+=b2f((u16)v[6]); achi[3]+=b2f((u16)v[7]);
    }
  f32x4 u0 = *(const f32x4*)&unary[gr*64 + c8*8];
  f32x4 u1 = *(const f32x4*)&unary[gr*64 + c8*8 + 4];
  float mk = mf[gr];
  f32x4 o0, o1;
  #pragma unroll
  for(int k=0;k<4;k++){ o0[k] = (u0[k] + aclo[k]) * mk; o1[k] = (u1[k] + achi[k]) * mk; }
  *(f32x4*)&outq[gr*64 + c8*8]     = o0;
  *(f32x4*)&outq[gr*64 + c8*8 + 4] = o1;
}

extern "C" void kernel_launch(void* const* d_in, const int* in_sizes, int n_in,
                              void* d_out, int out_size, void* d_ws, size_t ws_size,
                              hipStream_t stream) {
  const float* x       = (const float*)d_in[0];
  const int*   mask    = (const int*)d_in[1];
  const float* ternary = (const float*)d_in[2];
  const float* gw      = (const float*)d_in[3];
  float* out = (float*)d_out;

  const size_t NE = (size_t)BB*LL*64;          // 262144
  char* p = (char*)d_ws;
  auto alloc = [&](size_t bytes)->void*{
    void* r = (void*)p; p += (bytes + 255) & ~(size_t)255; return r;
  };
  float* unary   = (float*)alloc(NE*4);
  float* qzstate = (float*)alloc(NE*4);
  float* mf      = (float*)alloc((size_t)BB*LL*4);
  u16*   qzb     = (u16*)alloc(NE*2);
  u16*   t1b     = (u16*)alloc((size_t)BB*HH*LL*64*2);   // 4.2 MB
  u16*   t1t     = (u16*)alloc((size_t)BB*HH*LL*64*2);   // 4.2 MB
  u16*   t2t     = (u16*)alloc((size_t)BB*HH*LL*64*2);   // 4.2 MB
  float* MgF     = (float*)alloc(NE*4);                  // 1 MB
  u16*   miP2    = (u16*)alloc((size_t)2*BB*LL*512*2);   // 8.4 MB (2 K-halves)
  u16*   mjP     = (u16*)alloc((size_t)32*LL*512*2);     // 16.8 MB (4 it-partials)
  u16*   T4t     = (u16*)alloc(32768*2);
  u16*   Tt2     = (u16*)alloc(32768*2);
  u16*   Gt      = (u16*)alloc(4096*2);
  u16*   Gt2     = (u16*)alloc(4096*2);

  const int KF_LDS = 74624;  // t2sh 33792 + Pph 16896 + PpTs 18432 + red 1024 + redS 128 + stg32 4352
  hipFuncSetAttribute(reinterpret_cast<const void*>(kF),
                      hipFuncAttributeMaxDynamicSharedMemorySize, KF_LDS);

  kp_prep<<<128, 256, 0, stream>>>(ternary, gw, T4t, Tt2, Gt, Gt2);
  k0_init<<<(int)(NE/256), 256, 0, stream>>>(x, mask, unary, qzstate, mf);
  for(int it=0; it<4; ++it){
    kA<<<BB*8, 256, 0, stream>>>(qzstate, mask, Gt2, Gt, qzb, MgF);
    k2<<<512, 256, 0, stream>>>(qzb, T4t, Tt2, t1b, t1t, t2t);
    kF<<<512, 512, KF_LDS, stream>>>(t1b, qzb, t1t, t2t, mf, miP2, mjP);
    float* outq = (it==3) ? out : qzstate;
    k5c<<<128, 256, 0, stream>>>(miP2, mjP, MgF, unary, mf, outq);
  }
}

// Round 12
// 250.262 us; speedup vs baseline: 2.1558x; 1.6903x over previous
//
#include <hip/hip_runtime.h>

#define BB 8
#define LL 512
#define HH 8
#define BIGV (1e9f)

typedef unsigned short u16;
typedef __attribute__((ext_vector_type(8))) short bf16x8;
typedef __attribute__((ext_vector_type(4))) short s16x4;
typedef __attribute__((ext_vector_type(4))) float f32x4;

#define MFMA(a,b,c) __builtin_amdgcn_mfma_f32_16x16x32_bf16(a,b,c,0,0,0)

__device__ __forceinline__ u16 f2b(float f){
  unsigned u = __float_as_uint(f);
  u = (u + 0x7fffu + ((u>>16)&1u)) >> 16;
  return (u16)u;
}
__device__ __forceinline__ float b2f(u16 s){ return __uint_as_float(((unsigned)s)<<16); }
__device__ __forceinline__ bf16x8 ldb8(const u16* p){ return *(const bf16x8*)p; }

__device__ __forceinline__ float g16_sum(float v){
  v += __shfl_xor(v,1,64); v += __shfl_xor(v,2,64);
  v += __shfl_xor(v,4,64); v += __shfl_xor(v,8,64);
  return v;
}

// ---- tables: T4t[c][b][a], Tt2[c][a][b], Gt[a][j], Gt2[j][a] ----
__global__ void kp_prep(const float* __restrict__ T, const float* __restrict__ gw,
                        u16* __restrict__ T4t, u16* __restrict__ Tt2,
                        u16* __restrict__ Gt, u16* __restrict__ Gt2){
  int idx = blockIdx.x*256 + threadIdx.x;   // < 32768
  { int c=idx>>12, b=(idx>>6)&63, a=idx&63; T4t[idx] = f2b(T[(a*64+b)*8+c]); }
  { int c=idx>>12, a=(idx>>6)&63, b=idx&63; Tt2[idx] = f2b(T[(a*64+b)*8+c]); }
  if(idx < 4096){
    int a=idx>>6, j=idx&63;
    Gt[idx]  = f2b(gw[j*64+a]);   // Gt[a][j]
    Gt2[idx] = f2b(gw[idx]);      // Gt2[j][a]
  }
}

// ---- kCA: fused [new_qz from partials] + [row softmax, in-register] + [P2/Mg] ----
// mode 0: new_qz = (x+pe)*mk (init; writes unary/mf) ; mode 1: new_qz from
// MgF/miP/mjP partials ; mode 2: final — write new_qz to out, skip softmax/P2.
// Grid 64 = (z = bid&7, itile<8), 256 threads. Rows itile*64..+64.
__global__ __launch_bounds__(256) void kCA(const float* __restrict__ x, const int* __restrict__ mask,
      const u16* __restrict__ miP, const u16* __restrict__ mjP, const float* __restrict__ MgF_in,
      float* __restrict__ unary, float* __restrict__ mf,
      const u16* __restrict__ Gt2, const u16* __restrict__ Gt,
      u16* __restrict__ qzb, float* __restrict__ MgF_out, float* __restrict__ out, int mode){
  __shared__ u16 qlds[64*72];
  __shared__ u16 P2s[64*72];
  int bid = blockIdx.x; int z = bid & 7, itile = bid >> 3;   // z-affine for XCD L2
  int t = threadIdx.x, lane = t&63, w = t>>6, l15 = lane&15, lhi = lane>>4;
  int rbase = z*LL + itile*64;
  int c8 = t & 7;

  for(int p=0;p<2;p++){
    int rl = p*32 + (t>>3);            // local row 0..63 (8 threads per row)
    int rg = rbase + rl;
    float v[8]; float mk;
    if(mode == 0){
      mk = (mask[rg] != 0) ? 1.f : 0.f;
      if(c8 == 0) mf[rg] = mk;
      int pos = rg & (LL-1);
      #pragma unroll
      for(int k=0;k<8;k++){
        int d = c8*8 + k;
        float div = __expf(-(float)(d & ~1) * 0.14391156962f);  // ln(10000)/64
        float arg = (float)pos * div;
        float pe = (d & 1) ? cosf(arg) : sinf(arg);
        v[k] = (x[(size_t)rg*64 + d] + pe) * mk;
      }
      *(f32x4*)&unary[(size_t)rg*64 + c8*8]     = (f32x4){v[0],v[1],v[2],v[3]};
      *(f32x4*)&unary[(size_t)rg*64 + c8*8 + 4] = (f32x4){v[4],v[5],v[6],v[7]};
    } else {
      mk = mf[rg];
      const float* mgp = &MgF_in[(size_t)rg*64 + c8*8];
      f32x4 alo = *(const f32x4*)mgp;
      f32x4 ahi = *(const f32x4*)(mgp + 4);
      #pragma unroll
      for(int c=0;c<8;c++){
        bf16x8 vv = ldb8(&miP[(size_t)rg*512 + c*64 + c8*8]);
        alo[0]+=b2f((u16)vv[0]); alo[1]+=b2f((u16)vv[1]); alo[2]+=b2f((u16)vv[2]); alo[3]+=b2f((u16)vv[3]);
        ahi[0]+=b2f((u16)vv[4]); ahi[1]+=b2f((u16)vv[5]); ahi[2]+=b2f((u16)vv[6]); ahi[3]+=b2f((u16)vv[7]);
      }
      #pragma unroll
      for(int s=0;s<4;s++)
        #pragma unroll
        for(int c=0;c<8;c++){
          bf16x8 vv = ldb8(&mjP[(((size_t)(s*8 + z))*LL + rl + itile*64)*512 + c*64 + c8*8]);
          alo[0]+=b2f((u16)vv[0]); alo[1]+=b2f((u16)vv[1]); alo[2]+=b2f((u16)vv[2]); alo[3]+=b2f((u16)vv[3]);
          ahi[0]+=b2f((u16)vv[4]); ahi[1]+=b2f((u16)vv[5]); ahi[2]+=b2f((u16)vv[6]); ahi[3]+=b2f((u16)vv[7]);
        }
      f32x4 u0 = *(const f32x4*)&unary[(size_t)rg*64 + c8*8];
      f32x4 u1 = *(const f32x4*)&unary[(size_t)rg*64 + c8*8 + 4];
      #pragma unroll
      for(int k=0;k<4;k++){ v[k] = (u0[k] + alo[k]) * mk; v[4+k] = (u1[k] + ahi[k]) * mk; }
    }
    if(mode == 2){
      *(f32x4*)&out[(size_t)rg*64 + c8*8]     = (f32x4){v[0],v[1],v[2],v[3]};
      *(f32x4*)&out[(size_t)rg*64 + c8*8 + 4] = (f32x4){v[4],v[5],v[6],v[7]};
      continue;
    }
    // ---- in-register row softmax: 8 lanes per row (lane group = c8) ----
    float mx = v[0];
    #pragma unroll
    for(int k=1;k<8;k++) mx = fmaxf(mx, v[k]);
    mx = fmaxf(mx, __shfl_xor(mx,1,64));
    mx = fmaxf(mx, __shfl_xor(mx,2,64));
    mx = fmaxf(mx, __shfl_xor(mx,4,64));
    float s = 0.f;
    #pragma unroll
    for(int k=0;k<8;k++){ v[k] = __expf(v[k]-mx); s += v[k]; }
    s += __shfl_xor(s,1,64); s += __shfl_xor(s,2,64); s += __shfl_xor(s,4,64);
    float iv = mk / s;
    bf16x8 q8;
    #pragma unroll
    for(int k=0;k<8;k++) q8[k] = (short)f2b(v[k]*iv);
    *(bf16x8*)&qzb[(size_t)rg*64 + c8*8] = q8;
    *(bf16x8*)&qlds[rl*72 + c8*8] = q8;
  }
  if(mode == 2) return;
  __syncthreads();
  // ---- P2 = rowsoftmax(qz @ gw^T) (fixed-max exp: logits bounded ~|gw|) ----
  f32x4 f[4];
  {
    const u16* Ar = &qlds[(w*16 + l15)*72 + lhi*8];
    bf16x8 a0 = ldb8(Ar), a1 = ldb8(Ar+32);
    #pragma unroll
    for(int ct=0;ct<4;ct++){
      const u16* Br = Gt2 + (size_t)(ct*16 + l15)*64 + lhi*8;
      f32x4 acc = {0.f,0.f,0.f,0.f};
      acc = MFMA(a0, ldb8(Br), acc);
      acc = MFMA(a1, ldb8(Br+32), acc);
      f[ct] = acc;
    }
  }
  #pragma unroll
  for(int jj=0;jj<4;jj++){
    float ps = 0.f;
    #pragma unroll
    for(int ct=0;ct<4;ct++){ float e = __expf(f[ct][jj]); f[ct][jj] = e; ps += e; }
    float s = g16_sum(ps);
    float iv = 1.f/s;
    #pragma unroll
    for(int ct=0;ct<4;ct++)
      P2s[(w*16 + lhi*4 + jj)*72 + ct*16 + l15] = f2b(f[ct][jj]*iv);
  }
  __syncthreads();
  // ---- Mg[i,a] = sum_j P2[i,j] gw[j,a] ----
  {
    const u16* Ar = &P2s[(w*16 + l15)*72 + lhi*8];
    bf16x8 a0 = ldb8(Ar), a1 = ldb8(Ar+32);
    #pragma unroll
    for(int nt=0;nt<4;nt++){
      const u16* Br = Gt + (size_t)(nt*16 + l15)*64 + lhi*8;
      f32x4 acc = {0.f,0.f,0.f,0.f};
      acc = MFMA(a0, ldb8(Br), acc);
      acc = MFMA(a1, ldb8(Br+32), acc);
      #pragma unroll
      for(int jj=0;jj<4;jj++)
        MgF_out[((size_t)rbase + w*16 + lhi*4 + jj)*64 + nt*16 + l15] = acc[jj];
    }
  }
}

// ---- k2: per (z,c): t1[i][b], t1t[b][i], t2t[a][j]  (all K=64 GEMMs) ----
__global__ __launch_bounds__(256) void k2(const u16* __restrict__ qzb,
      const u16* __restrict__ T4t, const u16* __restrict__ Tt2,
      u16* __restrict__ t1b, u16* __restrict__ t1t, u16* __restrict__ t2t){
  int bid = blockIdx.x; int z = bid&7, c = (bid>>3)&7, itile = bid>>6;
  int zc = z*8 + c;
  int t = threadIdx.x, lane = t&63, w = t>>6, l15 = lane&15, lhi = lane>>4;
  int i0 = itile*64;
  const u16* qA = qzb + ((size_t)z*LL + i0 + w*16 + l15)*64 + lhi*8;
  bf16x8 qa0 = ldb8(qA), qa1 = ldb8(qA+32);
  const u16* tA = T4t + c*4096 + (w*16 + l15)*64 + lhi*8;
  bf16x8 ta0 = ldb8(tA), ta1 = ldb8(tA+32);
  const u16* uA = Tt2 + c*4096 + (w*16 + l15)*64 + lhi*8;
  bf16x8 ua0 = ldb8(uA), ua1 = ldb8(uA+32);
  #pragma unroll
  for(int nt=0;nt<4;nt++){
    {
      const u16* Br = T4t + c*4096 + (nt*16 + l15)*64 + lhi*8;
      f32x4 acc = {0.f,0.f,0.f,0.f};
      acc = MFMA(qa0, ldb8(Br), acc);
      acc = MFMA(qa1, ldb8(Br+32), acc);
      #pragma unroll
      for(int jj=0;jj<4;jj++)
        t1b[((size_t)zc*LL + i0 + w*16 + lhi*4 + jj)*64 + nt*16 + l15] = f2b(acc[jj]);
    }
    const u16* Br = qzb + ((size_t)z*LL + i0 + nt*16 + l15)*64 + lhi*8;
    bf16x8 qb0 = ldb8(Br), qb1 = ldb8(Br+32);
    {
      f32x4 acc = {0.f,0.f,0.f,0.f};
      acc = MFMA(ta0, qb0, acc);
      acc = MFMA(ta1, qb1, acc);
      #pragma unroll
      for(int jj=0;jj<4;jj++)
        t1t[((size_t)zc*64 + w*16 + lhi*4 + jj)*LL + i0 + nt*16 + l15] = f2b(acc[jj]);
    }
    {
      f32x4 acc = {0.f,0.f,0.f,0.f};
      acc = MFMA(ua0, qb0, acc);
      acc = MFMA(ua1, qb1, acc);
      #pragma unroll
      for(int jj=0;jj<4;jj++)
        t2t[((size_t)zc*64 + w*16 + lhi*4 + jj)*LL + i0 + nt*16 + l15] = f2b(acc[jj]);
    }
  }
}

// ---- kF: byte-identical to round 9 (verified 43.6us / FETCH 9MB) ----
__global__ __launch_bounds__(1024) void kF(const u16* __restrict__ t1b, const u16* __restrict__ qzb,
        const u16* __restrict__ t1t, const u16* __restrict__ t2t, const float* __restrict__ mf,
        u16* __restrict__ miP, u16* __restrict__ mjP){
  extern __shared__ char smem[];
  u16*   t2s  = (u16*)smem;                    // [64][520]   66560 B
  u16*   Pp   = (u16*)(smem + 66560);          // [32][520]   33280 B (unnormalized exp)
  u16*   PpT  = (u16*)(smem + 99840);          // [16w][32][40] 40960 B (normalized, wave-local)
  float* red  = (float*)(smem + 140800);       // [32][16]     2048 B
  float* redS = (float*)(smem + 142848);       // [32]          128 B
  float* stgf = (float*)(smem + 142976);       // [2][32][68] f32 17408 B  (end 160384)
  u16*   stg  = (u16*)smem;                    // [512][72] dump (reuses t2s+Pp, 73728 B)
  int bid = blockIdx.x;
  int z = bid&7, c = (bid>>3)&7, it = bid>>6;   // it < 4
  int zc = z*8 + c;
  int t = threadIdx.x, lane = t&63, w = t>>6, l15 = lane&15, lhi = lane>>4;
  int jc0 = w*32;                               // wave's j-slice
  int h = w>>3, wr = (w>>2)&1, wc = w&3;        // mi role
  #pragma unroll
  for(int m=0;m<4;m++){
    int e = (m*1024 + t)*8;
    int a = e >> 9, j = e & 511;
    *(bf16x8*)&t2s[a*520 + j] = ldb8(t2t + ((size_t)zc*64 + a)*LL + j);
  }
  float mfj[2];
  mfj[0] = mf[z*LL + jc0 + l15];
  mfj[1] = mf[z*LL + jc0 + 16 + l15];
  f32x4 mj[2][4];
  #pragma unroll
  for(int jt=0;jt<2;jt++)
    #pragma unroll
    for(int bt=0;bt<4;bt++) mj[jt][bt] = (f32x4){0.f,0.f,0.f,0.f};
  u16* PpTw = PpT + w*32*40;                    // wave-local transpose buffer

  for(int ip=0; ip<4; ++ip){
    int i0g = it*128 + ip*32;
    f32x4 S[2][2];
    #pragma unroll
    for(int rt=0;rt<2;rt++){ S[rt][0] = (f32x4){0,0,0,0}; S[rt][1] = (f32x4){0,0,0,0}; }
    #pragma unroll
    for(int rt=0;rt<2;rt++){
      const u16* Ar = t1b + ((size_t)zc*LL + i0g + rt*16 + l15)*64 + lhi*8;
      bf16x8 a0 = ldb8(Ar), a1 = ldb8(Ar+32);
      #pragma unroll
      for(int ct=0;ct<2;ct++){
        const u16* Br = qzb + ((size_t)z*LL + jc0 + ct*16 + l15)*64 + lhi*8;
        S[rt][ct] = MFMA(a0, ldb8(Br), S[rt][ct]);
        S[rt][ct] = MFMA(a1, ldb8(Br+32), S[rt][ct]);
      }
    }
    #pragma unroll
    for(int rt=0;rt<2;rt++)
      #pragma unroll
      for(int jj=0;jj<4;jj++){
        int rloc = rt*16 + lhi*4 + jj;
        int irow = i0g + rloc;
        float mfi = mf[z*LL + irow];
        float ps = 0.f;
        #pragma unroll
        for(int ct=0;ct<2;ct++){
          int jcol = jc0 + ct*16 + l15;
          float v = S[rt][ct][jj] - ((irow==jcol)?BIGV:0.f);
          float e = mfi * mfj[ct] * __expf(v);
          S[rt][ct][jj] = e; ps += e;
          Pp[rloc*520 + jcol] = f2b(e);        // unnormalized
        }
        ps = g16_sum(ps);
        if(l15 == 0) red[rloc*16 + w] = ps;
      }
    __syncthreads();                            // B1: Pp/red (and t2s, ip=0) ready
    if(t < 512){
      float v = red[t];
      v += __shfl_xor(v,1,64); v += __shfl_xor(v,2,64);
      v += __shfl_xor(v,4,64); v += __shfl_xor(v,8,64);
      if((t&15)==0) redS[t>>4] = v;
    }
    __syncthreads();                            // B1.5: redS ready
    float ivv[2][4];
    #pragma unroll
    for(int rt=0;rt<2;rt++)
      #pragma unroll
      for(int jj=0;jj<4;jj++){
        float s = redS[rt*16 + lhi*4 + jj];
        ivv[rt][jj] = s > 0.f ? 1.f/s : 0.f;
      }
    #pragma unroll
    for(int rt=0;rt<2;rt++)
      #pragma unroll
      for(int ct=0;ct<2;ct++){
        s16x4 v4 = { (short)f2b(S[rt][ct][0]*ivv[rt][0]), (short)f2b(S[rt][ct][1]*ivv[rt][1]),
                     (short)f2b(S[rt][ct][2]*ivv[rt][2]), (short)f2b(S[rt][ct][3]*ivv[rt][3]) };
        *(s16x4*)&PpTw[(ct*16 + l15)*40 + rt*16 + lhi*4] = v4;
      }
    {
      f32x4 mia = {0.f,0.f,0.f,0.f};
      const u16* Ab = Pp + (wr*16 + l15)*520 + h*256 + lhi*8;
      const u16* Bb = t2s + (wc*16 + l15)*520 + h*256 + lhi*8;
      #pragma unroll
      for(int ks=0;ks<8;ks++)
        mia = MFMA(ldb8(Ab + ks*32), ldb8(Bb + ks*32), mia);
      #pragma unroll
      for(int jj=0;jj<4;jj++)
        stgf[(h*32 + wr*16 + lhi*4 + jj)*68 + wc*16 + l15] = mia[jj]*ivv[wr][jj];
    }
    {
      bf16x8 av[2];
      #pragma unroll
      for(int jt=0;jt<2;jt++)
        av[jt] = ldb8(PpTw + (jt*16 + l15)*40 + lhi*8);
      #pragma unroll
      for(int bt=0;bt<4;bt++){
        bf16x8 b = ldb8(t1t + ((size_t)zc*64 + bt*16 + l15)*LL + i0g + lhi*8);
        #pragma unroll
        for(int jt=0;jt<2;jt++) mj[jt][bt] = MFMA(av[jt], b, mj[jt][bt]);
      }
    }
    __syncthreads();                            // B2: stgf ready; Pp/red/t2s reads done
    if(t < 512){
      int r = t>>4, cc = t&15;
      f32x4 v0 = *(const f32x4*)&stgf[r*68 + cc*4];
      f32x4 v1 = *(const f32x4*)&stgf[(32+r)*68 + cc*4];
      s16x4 o = { (short)f2b(v0[0]+v1[0]), (short)f2b(v0[1]+v1[1]),
                  (short)f2b(v0[2]+v1[2]), (short)f2b(v0[3]+v1[3]) };
      *(s16x4*)&miP[((size_t)z*LL + i0g + r)*512 + c*64 + cc*4] = o;
    }
  }
  #pragma unroll
  for(int jt=0;jt<2;jt++)
    #pragma unroll
    for(int bt=0;bt<4;bt++)
      #pragma unroll
      for(int jj=0;jj<4;jj++)
        stg[(jc0 + jt*16 + lhi*4 + jj)*72 + bt*16 + l15] = f2b(mj[jt][bt][jj]);
  __syncthreads();
  #pragma unroll
  for(int q=0;q<4;q++){
    int e = q*1024 + t;
    int j = e >> 3, ch = e & 7;
    *(bf16x8*)&mjP[(((size_t)(it*8 + z))*LL + j)*512 + c*64 + ch*8]
      = *(const bf16x8*)&stg[j*72 + ch*8];
  }
}

extern "C" void kernel_launch(void* const* d_in, const int* in_sizes, int n_in,
                              void* d_out, int out_size, void* d_ws, size_t ws_size,
                              hipStream_t stream) {
  const float* x       = (const float*)d_in[0];
  const int*   mask    = (const int*)d_in[1];
  const float* ternary = (const float*)d_in[2];
  const float* gw      = (const float*)d_in[3];
  float* out = (float*)d_out;

  const size_t NE = (size_t)BB*LL*64;          // 262144
  char* p = (char*)d_ws;
  auto alloc = [&](size_t bytes)->void*{
    void* r = (void*)p; p += (bytes + 255) & ~(size_t)255; return r;
  };
  float* unary   = (float*)alloc(NE*4);
  float* mf      = (float*)alloc((size_t)BB*LL*4);
  u16*   qzb     = (u16*)alloc(NE*2);
  u16*   t1b     = (u16*)alloc((size_t)BB*HH*LL*64*2);   // 4.2 MB
  u16*   t1t     = (u16*)alloc((size_t)BB*HH*LL*64*2);   // 4.2 MB
  u16*   t2t     = (u16*)alloc((size_t)BB*HH*LL*64*2);   // 4.2 MB
  float* MgF     = (float*)alloc(NE*4);                  // 1 MB
  u16*   miP     = (u16*)alloc((size_t)BB*LL*512*2);     // 4.2 MB
  u16*   mjP     = (u16*)alloc((size_t)32*LL*512*2);     // 16.8 MB (4 it-partials)
  u16*   T4t     = (u16*)alloc(32768*2);
  u16*   Tt2     = (u16*)alloc(32768*2);
  u16*   Gt      = (u16*)alloc(4096*2);
  u16*   Gt2     = (u16*)alloc(4096*2);

  const int KF_LDS = 160384;  // t2s + Pp + PpT + red + redS + stgf
  hipFuncSetAttribute(reinterpret_cast<const void*>(kF),
                      hipFuncAttributeMaxDynamicSharedMemorySize, KF_LDS);

  kp_prep<<<128, 256, 0, stream>>>(ternary, gw, T4t, Tt2, Gt, Gt2);
  kCA<<<64, 256, 0, stream>>>(x, mask, miP, mjP, MgF, unary, mf, Gt2, Gt,
                              qzb, MgF, out, 0);
  for(int it=0; it<4; ++it){
    k2<<<512, 256, 0, stream>>>(qzb, T4t, Tt2, t1b, t1t, t2t);
    kF<<<256, 1024, KF_LDS, stream>>>(t1b, qzb, t1t, t2t, mf, miP, mjP);
    kCA<<<64, 256, 0, stream>>>(x, mask, miP, mjP, MgF, unary, mf, Gt2, Gt,
                                qzb, MgF, out, (it==3) ? 2 : 1);
  }
}

// Round 13
// 235.071 us; speedup vs baseline: 2.2951x; 1.0646x over previous
//
#include <hip/hip_runtime.h>

#define BB 8
#define LL 512
#define HH 8
#define BIGV (1e9f)

typedef unsigned short u16;
typedef __attribute__((ext_vector_type(8))) short bf16x8;
typedef __attribute__((ext_vector_type(4))) short s16x4;
typedef __attribute__((ext_vector_type(4))) float f32x4;

#define MFMA(a,b,c) __builtin_amdgcn_mfma_f32_16x16x32_bf16(a,b,c,0,0,0)

__device__ __forceinline__ u16 f2b(float f){
  unsigned u = __float_as_uint(f);
  u = (u + 0x7fffu + ((u>>16)&1u)) >> 16;
  return (u16)u;
}
__device__ __forceinline__ float b2f(u16 s){ return __uint_as_float(((unsigned)s)<<16); }
__device__ __forceinline__ bf16x8 ldb8(const u16* p){ return *(const bf16x8*)p; }

__device__ __forceinline__ float g16_sum(float v){
  v += __shfl_xor(v,1,64); v += __shfl_xor(v,2,64);
  v += __shfl_xor(v,4,64); v += __shfl_xor(v,8,64);
  return v;
}

// ---- tables: T4t[c][b][a], Tt2[c][a][b], Gt[a][j], Gt2[j][a] ----
__global__ void kp_prep(const float* __restrict__ T, const float* __restrict__ gw,
                        u16* __restrict__ T4t, u16* __restrict__ Tt2,
                        u16* __restrict__ Gt, u16* __restrict__ Gt2){
  int idx = blockIdx.x*256 + threadIdx.x;   // < 32768
  { int c=idx>>12, b=(idx>>6)&63, a=idx&63; T4t[idx] = f2b(T[(a*64+b)*8+c]); }
  { int c=idx>>12, a=(idx>>6)&63, b=idx&63; Tt2[idx] = f2b(T[(a*64+b)*8+c]); }
  if(idx < 4096){
    int a=idx>>6, j=idx&63;
    Gt[idx]  = f2b(gw[j*64+a]);   // Gt[a][j]
    Gt2[idx] = f2b(gw[idx]);      // Gt2[j][a]
  }
}

// ---- kCA: fused [new_qz] + [row softmax in-register] + [P2/Mg MFMA] ----
// 256 blocks (z = bid&7, itile<32) x 16 rows: 4x the memory-level parallelism
// of the round-12 64-block version (its mjP/miP reads were latency-exposed).
__global__ __launch_bounds__(256) void kCA(const float* __restrict__ x, const int* __restrict__ mask,
      const u16* __restrict__ miP, const u16* __restrict__ mjP, const float* __restrict__ MgF_in,
      float* __restrict__ unary, float* __restrict__ mf,
      const u16* __restrict__ Gt2, const u16* __restrict__ Gt,
      u16* __restrict__ qzb, float* __restrict__ MgF_out, float* __restrict__ out, int mode){
  __shared__ u16 qlds[16*72];
  __shared__ u16 P2s[16*72];
  __shared__ float red2[16*4];
  int bid = blockIdx.x; int z = bid & 7, itile = bid >> 3;   // z-affine for XCD L2
  int t = threadIdx.x, lane = t&63, w = t>>6, l15 = lane&15, lhi = lane>>4;
  int rbase = z*LL + itile*16;
  {
    int row16 = t>>4, c4 = t&15;
    int rg = rbase + row16;
    float v[4]; float mk;
    if(mode == 0){
      mk = (mask[rg] != 0) ? 1.f : 0.f;
      if(c4 == 0) mf[rg] = mk;
      int pos = rg & (LL-1);
      #pragma unroll
      for(int k=0;k<4;k++){
        int d = c4*4 + k;
        float div = __expf(-(float)(d & ~1) * 0.14391156962f);  // ln(10000)/64
        float arg = (float)pos * div;
        float pe = (d & 1) ? cosf(arg) : sinf(arg);
        v[k] = (x[(size_t)rg*64 + d] + pe) * mk;
      }
      *(f32x4*)&unary[(size_t)rg*64 + c4*4] = (f32x4){v[0],v[1],v[2],v[3]};
    } else {
      mk = mf[rg];
      f32x4 acc = *(const f32x4*)&MgF_in[(size_t)rg*64 + c4*4];
      #pragma unroll
      for(int c=0;c<8;c++){
        s16x4 vv = *(const s16x4*)&miP[(size_t)rg*512 + c*64 + c4*4];
        acc[0]+=b2f((u16)vv[0]); acc[1]+=b2f((u16)vv[1]);
        acc[2]+=b2f((u16)vv[2]); acc[3]+=b2f((u16)vv[3]);
      }
      #pragma unroll
      for(int s=0;s<4;s++)
        #pragma unroll
        for(int c=0;c<8;c++){
          s16x4 vv = *(const s16x4*)&mjP[(((size_t)(s*8+z))*LL + itile*16 + row16)*512 + c*64 + c4*4];
          acc[0]+=b2f((u16)vv[0]); acc[1]+=b2f((u16)vv[1]);
          acc[2]+=b2f((u16)vv[2]); acc[3]+=b2f((u16)vv[3]);
        }
      f32x4 u0 = *(const f32x4*)&unary[(size_t)rg*64 + c4*4];
      #pragma unroll
      for(int k=0;k<4;k++) v[k] = (u0[k] + acc[k]) * mk;
    }
    if(mode == 2){
      *(f32x4*)&out[(size_t)rg*64 + c4*4] = (f32x4){v[0],v[1],v[2],v[3]};
      return;   // uniform across block: no barrier reached
    }
    // in-register row softmax: 16 lanes per row (group = c4)
    float mx = fmaxf(fmaxf(v[0],v[1]), fmaxf(v[2],v[3]));
    mx = fmaxf(mx, __shfl_xor(mx,1,64));
    mx = fmaxf(mx, __shfl_xor(mx,2,64));
    mx = fmaxf(mx, __shfl_xor(mx,4,64));
    mx = fmaxf(mx, __shfl_xor(mx,8,64));
    float s = 0.f;
    #pragma unroll
    for(int k=0;k<4;k++){ v[k] = __expf(v[k]-mx); s += v[k]; }
    s += __shfl_xor(s,1,64); s += __shfl_xor(s,2,64);
    s += __shfl_xor(s,4,64); s += __shfl_xor(s,8,64);
    float iv = mk / s;
    s16x4 q4 = { (short)f2b(v[0]*iv), (short)f2b(v[1]*iv),
                 (short)f2b(v[2]*iv), (short)f2b(v[3]*iv) };
    *(s16x4*)&qzb[(size_t)rg*64 + c4*4] = q4;
    *(s16x4*)&qlds[row16*72 + c4*4] = q4;
  }
  __syncthreads();
  // ---- P2 = rowsoftmax(qz @ gw^T), one 16x16 quadrant per wave (fixed-max exp) ----
  float fv[4];
  {
    bf16x8 a0 = ldb8(&qlds[l15*72 + lhi*8]);
    bf16x8 a1 = ldb8(&qlds[l15*72 + lhi*8 + 32]);
    const u16* Br = Gt2 + (size_t)(w*16 + l15)*64 + lhi*8;
    f32x4 acc = {0.f,0.f,0.f,0.f};
    acc = MFMA(a0, ldb8(Br), acc);
    acc = MFMA(a1, ldb8(Br+32), acc);
    #pragma unroll
    for(int jj=0;jj<4;jj++){
      float e = __expf(acc[jj]);
      fv[jj] = e;
      float p = g16_sum(e);
      if(l15==0) red2[(lhi*4+jj)*4 + w] = p;
    }
  }
  __syncthreads();
  #pragma unroll
  for(int jj=0;jj<4;jj++){
    int r = lhi*4+jj;
    float s = red2[r*4+0]+red2[r*4+1]+red2[r*4+2]+red2[r*4+3];
    float iv = 1.f/s;
    P2s[r*72 + w*16 + l15] = f2b(fv[jj]*iv);
  }
  __syncthreads();
  // ---- Mg[i,a] = sum_j P2[i,j] gw[j,a]; a-quadrant per wave ----
  {
    bf16x8 a0 = ldb8(&P2s[l15*72 + lhi*8]);
    bf16x8 a1 = ldb8(&P2s[l15*72 + lhi*8 + 32]);
    const u16* Br = Gt + (size_t)(w*16 + l15)*64 + lhi*8;
    f32x4 acc = {0.f,0.f,0.f,0.f};
    acc = MFMA(a0, ldb8(Br), acc);
    acc = MFMA(a1, ldb8(Br+32), acc);
    #pragma unroll
    for(int jj=0;jj<4;jj++)
      MgF_out[((size_t)rbase + lhi*4 + jj)*64 + w*16 + l15] = acc[jj];
  }
}

// ---- k2: per (z,c,itile): t1[i][b], t1t[b][i], t2t[a][j] — LDS-staged stores ----
// Round-12 version issued 48 scalar u16 global stores/lane (store-issue bound);
// now D-frags go to LDS and dump as 6x16B per thread.
__global__ __launch_bounds__(256) void k2(const u16* __restrict__ qzb,
      const u16* __restrict__ T4t, const u16* __restrict__ Tt2,
      u16* __restrict__ t1b, u16* __restrict__ t1t, u16* __restrict__ t2t){
  __shared__ u16 s1[64*72];
  __shared__ u16 s2[64*72];
  __shared__ u16 s3[64*72];
  int bid = blockIdx.x; int z = bid&7, c = (bid>>3)&7, itile = bid>>6;
  int zc = z*8 + c;
  int t = threadIdx.x, lane = t&63, w = t>>6, l15 = lane&15, lhi = lane>>4;
  int i0 = itile*64;
  const u16* qA = qzb + ((size_t)z*LL + i0 + w*16 + l15)*64 + lhi*8;
  bf16x8 qa0 = ldb8(qA), qa1 = ldb8(qA+32);
  const u16* tA = T4t + c*4096 + (w*16 + l15)*64 + lhi*8;
  bf16x8 ta0 = ldb8(tA), ta1 = ldb8(tA+32);
  const u16* uA = Tt2 + c*4096 + (w*16 + l15)*64 + lhi*8;
  bf16x8 ua0 = ldb8(uA), ua1 = ldb8(uA+32);
  #pragma unroll
  for(int nt=0;nt<4;nt++){
    {
      const u16* Br = T4t + c*4096 + (nt*16 + l15)*64 + lhi*8;
      f32x4 acc = {0.f,0.f,0.f,0.f};
      acc = MFMA(qa0, ldb8(Br), acc);
      acc = MFMA(qa1, ldb8(Br+32), acc);
      #pragma unroll
      for(int jj=0;jj<4;jj++)
        s1[(w*16 + lhi*4 + jj)*72 + nt*16 + l15] = f2b(acc[jj]);
    }
    const u16* Br = qzb + ((size_t)z*LL + i0 + nt*16 + l15)*64 + lhi*8;
    bf16x8 qb0 = ldb8(Br), qb1 = ldb8(Br+32);
    {
      f32x4 acc = {0.f,0.f,0.f,0.f};
      acc = MFMA(ta0, qb0, acc);
      acc = MFMA(ta1, qb1, acc);
      #pragma unroll
      for(int jj=0;jj<4;jj++)
        s2[(w*16 + lhi*4 + jj)*72 + nt*16 + l15] = f2b(acc[jj]);
    }
    {
      f32x4 acc = {0.f,0.f,0.f,0.f};
      acc = MFMA(ua0, qb0, acc);
      acc = MFMA(ua1, qb1, acc);
      #pragma unroll
      for(int jj=0;jj<4;jj++)
        s3[(w*16 + lhi*4 + jj)*72 + nt*16 + l15] = f2b(acc[jj]);
    }
  }
  __syncthreads();
  #pragma unroll
  for(int p=0;p<2;p++){
    int r = p*32 + (t>>3), ch = t&7;
    *(bf16x8*)&t1b[((size_t)zc*LL + i0 + r)*64 + ch*8]   = *(const bf16x8*)&s1[r*72 + ch*8];
    *(bf16x8*)&t1t[((size_t)zc*64 + r)*LL + i0 + ch*8]   = *(const bf16x8*)&s2[r*72 + ch*8];
    *(bf16x8*)&t2t[((size_t)zc*64 + r)*LL + i0 + ch*8]   = *(const bf16x8*)&s3[r*72 + ch*8];
  }
}

// ---- kF: byte-identical to round 9/12 (verified 43.6us / FETCH 9MB) ----
__global__ __launch_bounds__(1024) void kF(const u16* __restrict__ t1b, const u16* __restrict__ qzb,
        const u16* __restrict__ t1t, const u16* __restrict__ t2t, const float* __restrict__ mf,
        u16* __restrict__ miP, u16* __restrict__ mjP){
  extern __shared__ char smem[];
  u16*   t2s  = (u16*)smem;                    // [64][520]   66560 B
  u16*   Pp   = (u16*)(smem + 66560);          // [32][520]   33280 B (unnormalized exp)
  u16*   PpT  = (u16*)(smem + 99840);          // [16w][32][40] 40960 B (normalized, wave-local)
  float* red  = (float*)(smem + 140800);       // [32][16]     2048 B
  float* redS = (float*)(smem + 142848);       // [32]          128 B
  float* stgf = (float*)(smem + 142976);       // [2][32][68] f32 17408 B  (end 160384)
  u16*   stg  = (u16*)smem;                    // [512][72] dump (reuses t2s+Pp, 73728 B)
  int bid = blockIdx.x;
  int z = bid&7, c = (bid>>3)&7, it = bid>>6;   // it < 4
  int zc = z*8 + c;
  int t = threadIdx.x, lane = t&63, w = t>>6, l15 = lane&15, lhi = lane>>4;
  int jc0 = w*32;                               // wave's j-slice
  int h = w>>3, wr = (w>>2)&1, wc = w&3;        // mi role
  #pragma unroll
  for(int m=0;m<4;m++){
    int e = (m*1024 + t)*8;
    int a = e >> 9, j = e & 511;
    *(bf16x8*)&t2s[a*520 + j] = ldb8(t2t + ((size_t)zc*64 + a)*LL + j);
  }
  float mfj[2];
  mfj[0] = mf[z*LL + jc0 + l15];
  mfj[1] = mf[z*LL + jc0 + 16 + l15];
  f32x4 mj[2][4];
  #pragma unroll
  for(int jt=0;jt<2;jt++)
    #pragma unroll
    for(int bt=0;bt<4;bt++) mj[jt][bt] = (f32x4){0.f,0.f,0.f,0.f};
  u16* PpTw = PpT + w*32*40;                    // wave-local transpose buffer

  for(int ip=0; ip<4; ++ip){
    int i0g = it*128 + ip*32;
    f32x4 S[2][2];
    #pragma unroll
    for(int rt=0;rt<2;rt++){ S[rt][0] = (f32x4){0,0,0,0}; S[rt][1] = (f32x4){0,0,0,0}; }
    #pragma unroll
    for(int rt=0;rt<2;rt++){
      const u16* Ar = t1b + ((size_t)zc*LL + i0g + rt*16 + l15)*64 + lhi*8;
      bf16x8 a0 = ldb8(Ar), a1 = ldb8(Ar+32);
      #pragma unroll
      for(int ct=0;ct<2;ct++){
        const u16* Br = qzb + ((size_t)z*LL + jc0 + ct*16 + l15)*64 + lhi*8;
        S[rt][ct] = MFMA(a0, ldb8(Br), S[rt][ct]);
        S[rt][ct] = MFMA(a1, ldb8(Br+32), S[rt][ct]);
      }
    }
    #pragma unroll
    for(int rt=0;rt<2;rt++)
      #pragma unroll
      for(int jj=0;jj<4;jj++){
        int rloc = rt*16 + lhi*4 + jj;
        int irow = i0g + rloc;
        float mfi = mf[z*LL + irow];
        float ps = 0.f;
        #pragma unroll
        for(int ct=0;ct<2;ct++){
          int jcol = jc0 + ct*16 + l15;
          float v = S[rt][ct][jj] - ((irow==jcol)?BIGV:0.f);
          float e = mfi * mfj[ct] * __expf(v);
          S[rt][ct][jj] = e; ps += e;
          Pp[rloc*520 + jcol] = f2b(e);        // unnormalized
        }
        ps = g16_sum(ps);
        if(l15 == 0) red[rloc*16 + w] = ps;
      }
    __syncthreads();                            // B1: Pp/red (and t2s, ip=0) ready
    if(t < 512){
      float v = red[t];
      v += __shfl_xor(v,1,64); v += __shfl_xor(v,2,64);
      v += __shfl_xor(v,4,64); v += __shfl_xor(v,8,64);
      if((t&15)==0) redS[t>>4] = v;
    }
    __syncthreads();                            // B1.5: redS ready
    float ivv[2][4];
    #pragma unroll
    for(int rt=0;rt<2;rt++)
      #pragma unroll
      for(int jj=0;jj<4;jj++){
        float s = redS[rt*16 + lhi*4 + jj];
        ivv[rt][jj] = s > 0.f ? 1.f/s : 0.f;
      }
    #pragma unroll
    for(int rt=0;rt<2;rt++)
      #pragma unroll
      for(int ct=0;ct<2;ct++){
        s16x4 v4 = { (short)f2b(S[rt][ct][0]*ivv[rt][0]), (short)f2b(S[rt][ct][1]*ivv[rt][1]),
                     (short)f2b(S[rt][ct][2]*ivv[rt][2]), (short)f2b(S[rt][ct][3]*ivv[rt][3]) };
        *(s16x4*)&PpTw[(ct*16 + l15)*40 + rt*16 + lhi*4] = v4;
      }
    {
      f32x4 mia = {0.f,0.f,0.f,0.f};
      const u16* Ab = Pp + (wr*16 + l15)*520 + h*256 + lhi*8;
      const u16* Bb = t2s + (wc*16 + l15)*520 + h*256 + lhi*8;
      #pragma unroll
      for(int ks=0;ks<8;ks++)
        mia = MFMA(ldb8(Ab + ks*32), ldb8(Bb + ks*32), mia);
      #pragma unroll
      for(int jj=0;jj<4;jj++)
        stgf[(h*32 + wr*16 + lhi*4 + jj)*68 + wc*16 + l15] = mia[jj]*ivv[wr][jj];
    }
    {
      bf16x8 av[2];
      #pragma unroll
      for(int jt=0;jt<2;jt++)
        av[jt] = ldb8(PpTw + (jt*16 + l15)*40 + lhi*8);
      #pragma unroll
      for(int bt=0;bt<4;bt++){
        bf16x8 b = ldb8(t1t + ((size_t)zc*64 + bt*16 + l15)*LL + i0g + lhi*8);
        #pragma unroll
        for(int jt=0;jt<2;jt++) mj[jt][bt] = MFMA(av[jt], b, mj[jt][bt]);
      }
    }
    __syncthreads();                            // B2: stgf ready; Pp/red/t2s reads done
    if(t < 512){
      int r = t>>4, cc = t&15;
      f32x4 v0 = *(const f32x4*)&stgf[r*68 + cc*4];
      f32x4 v1 = *(const f32x4*)&stgf[(32+r)*68 + cc*4];
      s16x4 o = { (short)f2b(v0[0]+v1[0]), (short)f2b(v0[1]+v1[1]),
                  (short)f2b(v0[2]+v1[2]), (short)f2b(v0[3]+v1[3]) };
      *(s16x4*)&miP[((size_t)z*LL + i0g + r)*512 + c*64 + cc*4] = o;
    }
  }
  #pragma unroll
  for(int jt=0;jt<2;jt++)
    #pragma unroll
    for(int bt=0;bt<4;bt++)
      #pragma unroll
      for(int jj=0;jj<4;jj++)
        stg[(jc0 + jt*16 + lhi*4 + jj)*72 + bt*16 + l15] = f2b(mj[jt][bt][jj]);
  __syncthreads();
  #pragma unroll
  for(int q=0;q<4;q++){
    int e = q*1024 + t;
    int j = e >> 3, ch = e & 7;
    *(bf16x8*)&mjP[(((size_t)(it*8 + z))*LL + j)*512 + c*64 + ch*8]
      = *(const bf16x8*)&stg[j*72 + ch*8];
  }
}

extern "C" void kernel_launch(void* const* d_in, const int* in_sizes, int n_in,
                              void* d_out, int out_size, void* d_ws, size_t ws_size,
                              hipStream_t stream) {
  const float* x       = (const float*)d_in[0];
  const int*   mask    = (const int*)d_in[1];
  const float* ternary = (const float*)d_in[2];
  const float* gw      = (const float*)d_in[3];
  float* out = (float*)d_out;

  const size_t NE = (size_t)BB*LL*64;          // 262144
  char* p = (char*)d_ws;
  auto alloc = [&](size_t bytes)->void*{
    void* r = (void*)p; p += (bytes + 255) & ~(size_t)255; return r;
  };
  float* unary   = (float*)alloc(NE*4);
  float* mf      = (float*)alloc((size_t)BB*LL*4);
  u16*   qzb     = (u16*)alloc(NE*2);
  u16*   t1b     = (u16*)alloc((size_t)BB*HH*LL*64*2);   // 4.2 MB
  u16*   t1t     = (u16*)alloc((size_t)BB*HH*LL*64*2);   // 4.2 MB
  u16*   t2t     = (u16*)alloc((size_t)BB*HH*LL*64*2);   // 4.2 MB
  float* MgF     = (float*)alloc(NE*4);                  // 1 MB
  u16*   miP     = (u16*)alloc((size_t)BB*LL*512*2);     // 4.2 MB
  u16*   mjP     = (u16*)alloc((size_t)32*LL*512*2);     // 16.8 MB (4 it-partials)
  u16*   T4t     = (u16*)alloc(32768*2);
  u16*   Tt2     = (u16*)alloc(32768*2);
  u16*   Gt      = (u16*)alloc(4096*2);
  u16*   Gt2     = (u16*)alloc(4096*2);

  const int KF_LDS = 160384;  // t2s + Pp + PpT + red + redS + stgf
  hipFuncSetAttribute(reinterpret_cast<const void*>(kF),
                      hipFuncAttributeMaxDynamicSharedMemorySize, KF_LDS);

  kp_prep<<<128, 256, 0, stream>>>(ternary, gw, T4t, Tt2, Gt, Gt2);
  kCA<<<256, 256, 0, stream>>>(x, mask, miP, mjP, MgF, unary, mf, Gt2, Gt,
                               qzb, MgF, out, 0);
  for(int it=0; it<4; ++it){
    k2<<<512, 256, 0, stream>>>(qzb, T4t, Tt2, t1b, t1t, t2t);
    kF<<<256, 1024, KF_LDS, stream>>>(t1b, qzb, t1t, t2t, mf, miP, mjP);
    kCA<<<256, 256, 0, stream>>>(x, mask, miP, mjP, MgF, unary, mf, Gt2, Gt,
                                 qzb, MgF, out, (it==3) ? 2 : 1);
  }
}